// Round 7
// baseline (273.503 us; speedup 1.0000x reference)
//
#include <hip/hip_runtime.h>
#include <hip/hip_bf16.h>
#include <math.h>

#define BB   4
#define SS   2048
#define INF_ 256
#define EMB  512
#define NH   8
#define HD   64
#define NT   8192

typedef unsigned short u16;
typedef unsigned int   u32;
typedef __attribute__((ext_vector_type(8))) short bf16x8;   // 8 bf16 = 4 VGPRs
typedef __attribute__((ext_vector_type(8))) unsigned short u16x8;
typedef __attribute__((ext_vector_type(4))) float f32x4;

constexpr float C2  = 0.06375871607f;    // (1/sqrt(512)) * log2(e)
constexpr float RB  = 0.005624549f;      // log2(1 + 2^-8): half-ulp pre-bias
constexpr float TB  = 1.00390625f;       // 1 + 2^-8
constexpr float EPS = 1e-5f;

__device__ __forceinline__ u16 f2bf(float v) {
    __hip_bfloat16 h = __float2bfloat16(v);
    return *(u16*)&h;
}
__device__ __forceinline__ float bf2f(u16 u) {
    __hip_bfloat16 h = *(__hip_bfloat16*)&u;
    return __bfloat162float(h);
}
__device__ __forceinline__ u16 ftrunc_bf(float v) {     // trunc + half-ulp bias
    return (u16)(__float_as_uint(v * TB) >> 16);
}
__device__ __forceinline__ f32x4 mfma16(bf16x8 a, bf16x8 b, f32x4 c) {
    return __builtin_amdgcn_mfma_f32_16x16x32_bf16(a, b, c, 0, 0, 0);
}
__device__ __forceinline__ void async16(const void* g, void* l) {
    __builtin_amdgcn_global_load_lds(
        (const __attribute__((address_space(1))) void*)g,
        (__attribute__((address_space(3))) void*)l, 16, 0, 0);
}
__device__ __forceinline__ int derive_flag(const u16* x) {
    const int lane = threadIdx.x & 63;
    const unsigned e = (x[lane * 2] >> 7) & 0xFF;
    float pl = (e == 0 || (e >= 110 && e <= 140)) ? 1.0f : 0.0f;
    #pragma unroll
    for (int o = 1; o < 64; o <<= 1) pl += __shfl_xor(pl, o);
    return pl < 32.0f;
}

// ---------------------------------------------------------------------------
// Fused prep: z 0..7 weight transpose W[K][M]->Wt[M][K] bf16; z=8 x->bf16;
// z=9 biases/ln params -> packed f32.
// ---------------------------------------------------------------------------
__global__ __launch_bounds__(256) void prep(
    const u16* __restrict__ xsrc,
    const void* w0, const void* w1, const void* w2, const void* w3,
    const void* w4, const void* w5, const void* w6, const void* w7,
    const void* p0, const void* p1, const void* p2, const void* p3,
    const void* p4, const void* p5, const void* p6, const void* p7,
    const void* p8, const void* p9, const void* p10, const void* p11,
    u16* __restrict__ xbf, u16* __restrict__ wt1, u16* __restrict__ wt2,
    u16* __restrict__ f1t, u16* __restrict__ f2t, float* __restrict__ small)
{
    const int isf = derive_flag(xsrc);
    const int z = blockIdx.z;
    const int tid = threadIdx.x;

    if (z < 8) {
        int K, M; const void* src; u16* dst;
        switch (z) {
            case 0: K=256;  M=512;  src=w0; dst=wt1;             break;
            case 1: K=256;  M=512;  src=w1; dst=wt1+512*256;     break;
            case 2: K=256;  M=512;  src=w2; dst=wt1+2*512*256;   break;
            case 3: K=512;  M=512;  src=w3; dst=wt2;             break;
            case 4: K=512;  M=512;  src=w4; dst=wt2+512*512;     break;
            case 5: K=512;  M=512;  src=w5; dst=wt2+2*512*512;   break;
            case 6: K=512;  M=1024; src=w6; dst=f1t;             break;
            default:K=1024; M=512;  src=w7; dst=f2t;             break;
        }
        const int m0 = blockIdx.x * 32, k0 = blockIdx.y * 32;
        if (m0 >= M || k0 >= K) return;
        __shared__ u16 t[32][33];
        const int tx = tid & 31, ty = tid >> 5;
        #pragma unroll
        for (int i = 0; i < 4; ++i) {
            const int kk = k0 + ty + i * 8;
            t[ty + i * 8][tx] = isf ? ftrunc_bf(((const float*)src)[(size_t)kk * M + m0 + tx])
                                    : ((const u16*)src)[(size_t)kk * M + m0 + tx];
        }
        __syncthreads();
        #pragma unroll
        for (int i = 0; i < 4; ++i) {
            const int mm = m0 + ty + i * 8;
            dst[(size_t)mm * K + k0 + tx] = t[tx][ty + i * 8];
        }
    } else if (z == 8) {
        const int bid = blockIdx.y * 32 + blockIdx.x;    // 0..1023
        const int base = bid * 2048 + tid * 8;
        if (isf) {
            #pragma unroll
            for (int j = 0; j < 8; ++j)
                xbf[base + j] = ftrunc_bf(((const float*)xsrc)[base + j]);
        } else {
            *(u16x8*)&xbf[base] = *(const u16x8*)&xsrc[base];
        }
    } else {
        const int bid = blockIdx.y * 32 + blockIdx.x;
        if (bid >= 28) return;
        const int e = bid * 256 + tid;
        int id, i;
        if (e < 3072)      { id = e >> 9;               i = e & 511;          }
        else if (e < 4096) { id = 6;                    i = e - 3072;         }
        else               { id = 7 + ((e - 4096) >> 9); i = (e - 4096) & 511; }
        const void* src;
        switch (id) {
            case 0: src = p0; break;  case 1: src = p1; break;
            case 2: src = p2; break;  case 3: src = p3; break;
            case 4: src = p4; break;  case 5: src = p5; break;
            case 6: src = p6; break;  case 7: src = p7; break;
            case 8: src = p8; break;  case 9: src = p9; break;
            case 10: src = p10; break; default: src = p11; break;
        }
        small[e] = isf ? ((const float*)src)[i] : bf2f(((const u16*)src)[i]);
    }
}

// ---------------------------------------------------------------------------
// MFMA GEMM, double-buffered: out[N,M] = act(A[N,K] @ Wt[M,K]^T + bias).
// TRxTC tile, BK=64, 2x2 waves, XOR-swizzled LDS, global_load_lds w=16.
// VOUT: for which==2, write transposed [B][H][HD][S] via LDS.
// ---------------------------------------------------------------------------
template <int TR, int TC, bool RELU, bool AWHICH, bool VOUT>
__global__ __launch_bounds__(256) void gemm_bt(
    const u16* __restrict__ Aall, const u16* __restrict__ Wtall,
    const float* __restrict__ ball, u16* __restrict__ out,
    u16* __restrict__ vtb, int N, int K, int M)
{
    constexpr int RT = TR / 32, CT = TC / 32;
    constexpr int AR = TR / 32, BR = TC / 32;    // staging rounds per buffer
    __shared__ __align__(16) u16 sA[2][TR * 64];
    __shared__ __align__(16) u16 sB[2][TC * 64];

    const int mtiles = M / TC;
    const int which = blockIdx.x / mtiles;
    const int colb  = blockIdx.x % mtiles;
    const int row0 = blockIdx.y * TR, col0 = colb * TC;
    const u16* A  = Aall + (AWHICH ? (size_t)which * N * K : 0);
    const u16* Wt = Wtall + (size_t)which * M * K;
    const float* bias = ball + (size_t)which * M;

    const int tid = threadIdx.x;
    const int lane = tid & 63, w = tid >> 6;
    const int wrow = (w & 1) * (TR / 2), wcol = (w >> 1) * (TC / 2);
    const int c = lane & 15, quad = lane >> 4;

    const u16* ap[AR]; const u16* bp[BR];
    #pragma unroll
    for (int i = 0; i < AR; ++i) {
        const int raw = i * 256 + tid, r = raw >> 3, ch = (raw & 7) ^ (r & 7);
        ap[i] = A + (size_t)(row0 + r) * K + ch * 8;
    }
    #pragma unroll
    for (int i = 0; i < BR; ++i) {
        const int raw = i * 256 + tid, r = raw >> 3, ch = (raw & 7) ^ (r & 7);
        bp[i] = Wt + (size_t)(col0 + r) * K + ch * 8;
    }
    auto stage = [&](int buf) {
        #pragma unroll
        for (int i = 0; i < AR; ++i) {
            async16(ap[i], (char*)&sA[buf][0] + (i * 256 + tid) * 16);
            ap[i] += 64;
        }
        #pragma unroll
        for (int i = 0; i < BR; ++i) {
            async16(bp[i], (char*)&sB[buf][0] + (i * 256 + tid) * 16);
            bp[i] += 64;
        }
    };
    stage(0);

    f32x4 acc[RT][CT] = {};
    const int nIter = K >> 6;

    for (int t = 0; t < nIter; ++t) {
        __syncthreads();                 // drains stage(t), issued 1 iter ago
        const int buf = t & 1;
        if (t + 1 < nIter) stage(buf ^ 1);

        #pragma unroll
        for (int kt = 0; kt < 2; ++kt) {
            bf16x8 af[RT], bfr[CT];
            #pragma unroll
            for (int rt = 0; rt < RT; ++rt) {
                const int r = wrow + rt * 16 + c;
                af[rt] = *(const bf16x8*)&sA[buf][(r * 8 + ((kt * 4 + quad) ^ (r & 7))) * 8];
            }
            #pragma unroll
            for (int ct = 0; ct < CT; ++ct) {
                const int r = wcol + ct * 16 + c;
                bfr[ct] = *(const bf16x8*)&sB[buf][(r * 8 + ((kt * 4 + quad) ^ (r & 7))) * 8];
            }
            #pragma unroll
            for (int rt = 0; rt < RT; ++rt)
                #pragma unroll
                for (int ct = 0; ct < CT; ++ct)
                    acc[rt][ct] = mfma16(af[rt], bfr[ct], acc[rt][ct]);
        }
    }

    if (VOUT && which == 2) {
        // transpose through LDS: smem[col][row], stride 136 (16B-aligned rows)
        u16* smem = &sA[0][0];
        __syncthreads();
        #pragma unroll
        for (int rt = 0; rt < RT; ++rt) {
            const int rowb = wrow + rt * 16 + quad * 4;
            #pragma unroll
            for (int ct = 0; ct < CT; ++ct) {
                const int col = wcol + ct * 16 + c;
                const float bb = bias[col0 + col];
                ushort4 pk;
                pk.x = ftrunc_bf(acc[rt][ct][0] + bb);
                pk.y = ftrunc_bf(acc[rt][ct][1] + bb);
                pk.z = ftrunc_bf(acc[rt][ct][2] + bb);
                pk.w = ftrunc_bf(acc[rt][ct][3] + bb);
                *(ushort4*)&smem[col * 136 + rowb] = pk;
            }
        }
        __syncthreads();
        const int dcol = tid >> 2, part = tid & 3;       // TC=64 cols, 4x32 rows
        const int hg = (col0 + dcol) >> 6, dd = (col0 + dcol) & 63;
        const int bb = row0 >> 11, s0 = row0 & 2047;
        u16* dst = vtb + ((size_t)(bb * NH + hg) * HD + dd) * SS + s0 + part * 32;
        #pragma unroll
        for (int j = 0; j < 4; ++j)
            *(u16x8*)&dst[j * 8] = *(const u16x8*)&smem[dcol * 136 + part * 32 + j * 8];
        return;
    }

    const size_t outW = (size_t)which * N * M;
    #pragma unroll
    for (int rt = 0; rt < RT; ++rt) {
        #pragma unroll
        for (int i = 0; i < 4; ++i) {
            const int row = row0 + wrow + rt * 16 + quad * 4 + i;
            #pragma unroll
            for (int ct = 0; ct < CT; ++ct) {
                const int col = col0 + wcol + ct * 16 + c;
                float v = acc[rt][ct][i] + bias[col];
                if (RELU) v = fmaxf(v, 0.0f);
                out[outW + (size_t)row * M + col] = ftrunc_bf(v);
            }
        }
    }
}

// ---------------------------------------------------------------------------
// MFMA flash attention. Q-tile 64 (grid 1024 = 4 blocks/CU), double-buffered
// K/V, XCD-pinned (b,h), no-max log2 softmax, bpermute P-exchange (no sP LDS).
// PV computed as O[d][q] = mfma(A=V^T, B=P), epilogue: 4 ushort4 stores/lane.
// ---------------------------------------------------------------------------
__global__ __launch_bounds__(256) void attn_mfma(
    const u16* __restrict__ q, const u16* __restrict__ k,
    const u16* __restrict__ vt, u16* __restrict__ ctx)
{
    __shared__ __align__(16) u16 sK[2][64 * 64];
    __shared__ __align__(16) u16 sV[2][64 * 64];

    const int tid = threadIdx.x;
    const int w = tid >> 6, lane = tid & 63;
    const int c = lane & 15, quad = lane >> 4;
    // XCD swizzle: id&7 = xcd; 128 slots/XCD = 4 bh x 32 q-tiles
    const int id = blockIdx.x;
    const int slot = id >> 3;
    const int bh = ((id & 7) << 2) | (slot >> 5);
    const int qt = slot & 31;
    const int b = bh >> 3, h = bh & 7;
    const int q0 = qt * 64;
    const size_t tokbase = (size_t)b * SS;
    const int hoff = h * HD;

    const int myq = q0 + w * 16 + c;
    bf16x8 qf[2];
    #pragma unroll
    for (int kt = 0; kt < 2; ++kt)
        qf[kt] = *(const bf16x8*)&q[(tokbase + myq) * EMB + hoff + kt * 32 + quad * 8];

    const u16* kp[2]; const u16* vp[2];
    #pragma unroll
    for (int i = 0; i < 2; ++i) {
        const int raw = i * 256 + tid, rr = raw >> 3, ch = (raw & 7) ^ (rr & 7);
        kp[i] = k + (tokbase + rr) * EMB + hoff + ch * 8;
        vp[i] = vt + ((size_t)(b * NH + h) * HD + rr) * SS + ch * 8;
    }
    auto stage = [&](int buf) {
        #pragma unroll
        for (int i = 0; i < 2; ++i) {
            async16(kp[i], (char*)&sK[buf][0] + (i * 256 + tid) * 16);
            kp[i] += 64 * EMB;
        }
        #pragma unroll
        for (int i = 0; i < 2; ++i) {
            async16(vp[i], (char*)&sV[buf][0] + (i * 256 + tid) * 16);
            vp[i] += 64;
        }
    };
    stage(0);

    // bpermute source-lane byte addrs (same c, quad' = (quad&1)*2 and +1)
    const int addr0 = (c + 16 * ((quad & 1) * 2)) * 4;
    const int addr1 = addr0 + 64;

    float l_lane = 0.0f;
    f32x4 accO[4] = {};

    for (int t = 0; t < SS / 64; ++t) {
        __syncthreads();
        const int buf = t & 1;
        if (t + 1 < SS / 64) stage(buf ^ 1);

        // S^T[key][q]: A = K-tile, B = Q^T. Lane (c,quad): q=c, keys mt*16+quad*4+i
        f32x4 accS[4] = {};
        #pragma unroll
        for (int mt = 0; mt < 4; ++mt) {
            const int key = mt * 16 + c;
            #pragma unroll
            for (int kt = 0; kt < 2; ++kt) {
                bf16x8 kf = *(const bf16x8*)&sK[buf][(key * 8 + ((kt * 4 + quad) ^ (key & 7))) * 8];
                accS[mt] = mfma16(kf, qf[kt], accS[mt]);
            }
        }

        // p = exp2(s*C2 + RB), pack bf16 pairs (keys +0,+1 | +2,+3 per u32)
        u32 pw[8];
        float ls = 0.0f;
        #pragma unroll
        for (int mt = 0; mt < 4; ++mt) {
            const float e0 = __builtin_amdgcn_exp2f(fmaf(accS[mt][0], C2, RB));
            const float e1 = __builtin_amdgcn_exp2f(fmaf(accS[mt][1], C2, RB));
            const float e2 = __builtin_amdgcn_exp2f(fmaf(accS[mt][2], C2, RB));
            const float e3 = __builtin_amdgcn_exp2f(fmaf(accS[mt][3], C2, RB));
            ls += (e0 + e1) + (e2 + e3);
            pw[2 * mt]     = __builtin_amdgcn_perm(__float_as_uint(e1), __float_as_uint(e0), 0x07060302u);
            pw[2 * mt + 1] = __builtin_amdgcn_perm(__float_as_uint(e3), __float_as_uint(e2), 0x07060302u);
        }
        l_lane += ls;

        // PV B-frag: lane (c,quad) needs P[q=c][key=32*kt+quad*8+j] via bpermute
        // from quads (quad&1)*2, (quad&1)*2+1 of pw[2m],pw[2m+1], m=(quad>>1)+2*kt
        #pragma unroll
        for (int kt = 0; kt < 2; ++kt) {
            const int m = (quad >> 1) + 2 * kt;
            union { u32 u[4]; bf16x8 v; } pb;
            pb.u[0] = (u32)__builtin_amdgcn_ds_bpermute(addr0, (int)pw[2 * m]);
            pb.u[1] = (u32)__builtin_amdgcn_ds_bpermute(addr0, (int)pw[2 * m + 1]);
            pb.u[2] = (u32)__builtin_amdgcn_ds_bpermute(addr1, (int)pw[2 * m]);
            pb.u[3] = (u32)__builtin_amdgcn_ds_bpermute(addr1, (int)pw[2 * m + 1]);
            // O[d][q] += V^T[d][key] * P[q][key]
            #pragma unroll
            for (int nt = 0; nt < 4; ++nt) {
                const int d = nt * 16 + c;
                bf16x8 vf = *(const bf16x8*)&sV[buf][(d * 8 + ((kt * 4 + quad) ^ (d & 7))) * 8];
                accO[nt] = mfma16(vf, pb.v, accO[nt]);
            }
        }
    }

    // l for q=c: sum over quads; all lanes of column c get it
    float l = l_lane;
    l += __shfl_xor(l, 16);
    l += __shfl_xor(l, 32);
    const float li = (l > 0.0f) ? (1.0f / l) : 0.0f;

    // accO[nt] C-layout: col=c=q, row=quad*4+i = d-within-tile
    const int tok = q0 + w * 16 + c;
    u16* dst = ctx + (tokbase + tok) * EMB + hoff + quad * 4;
    #pragma unroll
    for (int nt = 0; nt < 4; ++nt) {
        ushort4 pk;
        pk.x = ftrunc_bf(accO[nt][0] * li);
        pk.y = ftrunc_bf(accO[nt][1] * li);
        pk.z = ftrunc_bf(accO[nt][2] * li);
        pk.w = ftrunc_bf(accO[nt][3] * li);
        *(ushort4*)&dst[nt * 16] = pk;
    }
}

// ---------------------------------------------------------------------------
// Residual + LayerNorm over EMB=512, bf16 in, one wave per row.
// ---------------------------------------------------------------------------
__global__ __launch_bounds__(256) void ln_mid(
    const u16* __restrict__ a, const u16* __restrict__ b2,
    const float* __restrict__ g, const float* __restrict__ be,
    u16* __restrict__ outb)
{
    const int wave = threadIdx.x >> 6, lane = threadIdx.x & 63;
    const size_t row = (size_t)blockIdx.x * 4 + wave;
    const u16x8 av = *(const u16x8*)&a[row * EMB + lane * 8];
    const u16x8 bv = *(const u16x8*)&b2[row * EMB + lane * 8];
    float vals[8], sum = 0.0f;
    #pragma unroll
    for (int i = 0; i < 8; ++i) { vals[i] = bf2f(av[i]) + bf2f(bv[i]); sum += vals[i]; }
    #pragma unroll
    for (int o = 1; o < 64; o <<= 1) sum += __shfl_xor(sum, o);
    const float mu = sum * (1.0f / 512.0f);
    float vs = 0.0f;
    #pragma unroll
    for (int i = 0; i < 8; ++i) { const float d = vals[i] - mu; vs += d * d; }
    #pragma unroll
    for (int o = 1; o < 64; o <<= 1) vs += __shfl_xor(vs, o);
    const float rstd = rsqrtf(vs * (1.0f / 512.0f) + EPS);
    u16x8 ov;
    #pragma unroll
    for (int i = 0; i < 8; ++i) {
        const int col = lane * 8 + i;
        ov[i] = f2bf((vals[i] - mu) * rstd * g[col] + be[col]);
    }
    *(u16x8*)&outb[row * EMB + lane * 8] = ov;
}

__global__ __launch_bounds__(256) void ln_final(
    const u16* __restrict__ a, const u16* __restrict__ b2,
    const float* __restrict__ g, const float* __restrict__ be,
    void* __restrict__ dout, const u16* __restrict__ xsrc)
{
    const int isf = derive_flag(xsrc);
    const int wave = threadIdx.x >> 6, lane = threadIdx.x & 63;
    const size_t row = (size_t)blockIdx.x * 4 + wave;
    const u16x8 av = *(const u16x8*)&a[row * EMB + lane * 8];
    const u16x8 bv = *(const u16x8*)&b2[row * EMB + lane * 8];
    float vals[8], sum = 0.0f;
    #pragma unroll
    for (int i = 0; i < 8; ++i) { vals[i] = bf2f(av[i]) + bf2f(bv[i]); sum += vals[i]; }
    #pragma unroll
    for (int o = 1; o < 64; o <<= 1) sum += __shfl_xor(sum, o);
    const float mu = sum * (1.0f / 512.0f);
    float vs = 0.0f;
    #pragma unroll
    for (int i = 0; i < 8; ++i) { const float d = vals[i] - mu; vs += d * d; }
    #pragma unroll
    for (int o = 1; o < 64; o <<= 1) vs += __shfl_xor(vs, o);
    const float rstd = rsqrtf(vs * (1.0f / 512.0f) + EPS);
    if (isf) {
        #pragma unroll
        for (int i = 0; i < 8; ++i) {
            const int col = lane * 8 + i;
            ((float*)dout)[row * EMB + col] = (vals[i] - mu) * rstd * g[col] + be[col];
        }
    } else {
        u16x8 ov;
        #pragma unroll
        for (int i = 0; i < 8; ++i) {
            const int col = lane * 8 + i;
            ov[i] = f2bf((vals[i] - mu) * rstd * g[col] + be[col]);
        }
        *(u16x8*)&((u16*)dout)[row * EMB + lane * 8] = ov;
    }
}

// ---------------------------------------------------------------------------
extern "C" void kernel_launch(void* const* d_in, const int* in_sizes, int n_in,
                              void* d_out, int out_size, void* d_ws, size_t ws_size,
                              hipStream_t stream)
{
    char* ws = (char*)d_ws;
    float* small = (float*)(ws + 0);        // 7168 f32
    u16*   wt1   = (u16*)(ws + 32768);
    u16*   wt2   = (u16*)(ws + 819200);
    u16*   f1t   = (u16*)(ws + 2392064);
    u16*   f2t   = (u16*)(ws + 3440640);
    u16*   xbf   = (u16*)(ws + 4489216);
    u16*   h3    = (u16*)(ws + 8683520);    // [3][NT][512]; reused as h2 [NT][1024]
    u16*   qkv   = (u16*)(ws + 33849344);   // [3][NT][512] (v slot unused)
    u16*   vtb   = (u16*)(ws + 59015168);   // [B][H][64][S]
    u16*   ctxb  = (u16*)(ws + 67403776);
    u16*   x1b   = (u16*)(ws + 75792384);
    u16*   ffb   = (u16*)(ws + 84180992);

    const dim3 blk(256);
    const u16* xsrc = (const u16*)d_in[0];

    prep<<<dim3(32, 32, 10), blk, 0, stream>>>(
        xsrc,
        d_in[1], d_in[5], d_in[9], d_in[3], d_in[7], d_in[11], d_in[13], d_in[15],
        d_in[2], d_in[6], d_in[10], d_in[4], d_in[8], d_in[12],
        d_in[14], d_in[16], d_in[17], d_in[18], d_in[19], d_in[20],
        xbf, wt1, wt2, f1t, f2t, small);

    // qkv layer 1: h3[which] = relu(x @ W1 + b1)
    gemm_bt<128, 64, true, false, false><<<dim3(24, 64), blk, 0, stream>>>(
        xbf, wt1, small + 0, h3, nullptr, NT, INF_, EMB);
    // qkv layer 2: q,k -> qkv; v -> vtb (transposed epilogue)
    gemm_bt<128, 64, false, true, true><<<dim3(24, 64), blk, 0, stream>>>(
        h3, wt2, small + 1536, qkv, vtb, NT, EMB, EMB);

    attn_mfma<<<dim3(1024), blk, 0, stream>>>(
        qkv, qkv + (size_t)NT * EMB, vtb, ctxb);

    // x1 = LN(ctx + q)
    ln_mid<<<NT / 4, blk, 0, stream>>>(ctxb, qkv, small + 4608, small + 5120, x1b);

    // FFN
    u16* h2 = h3;
    gemm_bt<128, 64, true, false, false><<<dim3(16, 64), blk, 0, stream>>>(
        x1b, f1t, small + 3072, h2, nullptr, NT, EMB, 1024);
    gemm_bt<128, 64, false, false, false><<<dim3(8, 64), blk, 0, stream>>>(
        h2, f2t, small + 4096, ffb, nullptr, NT, 1024, EMB);

    // out = LN(x1 + ff)
    ln_final<<<NT / 4, blk, 0, stream>>>(x1b, ffb, small + 5632, small + 6144, d_out, xsrc);
}

// Round 8
// 259.305 us; speedup vs baseline: 1.0548x; 1.0548x over previous
//
#include <hip/hip_runtime.h>
#include <hip/hip_bf16.h>
#include <math.h>

#define BB   4
#define SS   2048
#define INF_ 256
#define EMB  512
#define NH   8
#define HD   64
#define NT   8192

typedef unsigned short u16;
typedef unsigned int   u32;
typedef __attribute__((ext_vector_type(8))) short bf16x8;   // 8 bf16 = 4 VGPRs
typedef __attribute__((ext_vector_type(8))) unsigned short u16x8;
typedef __attribute__((ext_vector_type(4))) float f32x4;

constexpr float C2  = 0.06375871607f;    // (1/sqrt(512)) * log2(e)
constexpr float RB  = 0.005624549f;      // log2(1 + 2^-8): half-ulp pre-bias
constexpr float TB  = 1.00390625f;       // 1 + 2^-8
constexpr float EPS = 1e-5f;

__device__ __forceinline__ u16 f2bf(float v) {
    __hip_bfloat16 h = __float2bfloat16(v);
    return *(u16*)&h;
}
__device__ __forceinline__ float bf2f(u16 u) {
    __hip_bfloat16 h = *(__hip_bfloat16*)&u;
    return __bfloat162float(h);
}
__device__ __forceinline__ u16 ftrunc_bf(float v) {     // trunc + half-ulp bias
    return (u16)(__float_as_uint(v * TB) >> 16);
}
__device__ __forceinline__ f32x4 mfma16(bf16x8 a, bf16x8 b, f32x4 c) {
    return __builtin_amdgcn_mfma_f32_16x16x32_bf16(a, b, c, 0, 0, 0);
}
__device__ __forceinline__ void async16(const void* g, void* l) {
    __builtin_amdgcn_global_load_lds(
        (const __attribute__((address_space(1))) void*)g,
        (__attribute__((address_space(3))) void*)l, 16, 0, 0);
}
__device__ __forceinline__ int derive_flag(const u16* x) {
    const int lane = threadIdx.x & 63;
    const unsigned e = (x[lane * 2] >> 7) & 0xFF;
    float pl = (e == 0 || (e >= 110 && e <= 140)) ? 1.0f : 0.0f;
    #pragma unroll
    for (int o = 1; o < 64; o <<= 1) pl += __shfl_xor(pl, o);
    return pl < 32.0f;
}

// ---------------------------------------------------------------------------
// Fused prep: z 0..7 weight transpose W[K][M]->Wt[M][K] bf16; z=8 x->bf16;
// z=9 biases/ln params -> packed f32.
// ---------------------------------------------------------------------------
__global__ __launch_bounds__(256) void prep(
    const u16* __restrict__ xsrc,
    const void* w0, const void* w1, const void* w2, const void* w3,
    const void* w4, const void* w5, const void* w6, const void* w7,
    const void* p0, const void* p1, const void* p2, const void* p3,
    const void* p4, const void* p5, const void* p6, const void* p7,
    const void* p8, const void* p9, const void* p10, const void* p11,
    u16* __restrict__ xbf, u16* __restrict__ wt1, u16* __restrict__ wt2,
    u16* __restrict__ f1t, u16* __restrict__ f2t, float* __restrict__ small)
{
    const int isf = derive_flag(xsrc);
    const int z = blockIdx.z;
    const int tid = threadIdx.x;

    if (z < 8) {
        int K, M; const void* src; u16* dst;
        switch (z) {
            case 0: K=256;  M=512;  src=w0; dst=wt1;             break;
            case 1: K=256;  M=512;  src=w1; dst=wt1+512*256;     break;
            case 2: K=256;  M=512;  src=w2; dst=wt1+2*512*256;   break;
            case 3: K=512;  M=512;  src=w3; dst=wt2;             break;
            case 4: K=512;  M=512;  src=w4; dst=wt2+512*512;     break;
            case 5: K=512;  M=512;  src=w5; dst=wt2+2*512*512;   break;
            case 6: K=512;  M=1024; src=w6; dst=f1t;             break;
            default:K=1024; M=512;  src=w7; dst=f2t;             break;
        }
        const int m0 = blockIdx.x * 32, k0 = blockIdx.y * 32;
        if (m0 >= M || k0 >= K) return;
        __shared__ u16 t[32][33];
        const int tx = tid & 31, ty = tid >> 5;
        #pragma unroll
        for (int i = 0; i < 4; ++i) {
            const int kk = k0 + ty + i * 8;
            t[ty + i * 8][tx] = isf ? ftrunc_bf(((const float*)src)[(size_t)kk * M + m0 + tx])
                                    : ((const u16*)src)[(size_t)kk * M + m0 + tx];
        }
        __syncthreads();
        #pragma unroll
        for (int i = 0; i < 4; ++i) {
            const int mm = m0 + ty + i * 8;
            dst[(size_t)mm * K + k0 + tx] = t[tx][ty + i * 8];
        }
    } else if (z == 8) {
        const int bid = blockIdx.y * 32 + blockIdx.x;    // 0..1023
        const int base = bid * 2048 + tid * 8;
        if (isf) {
            #pragma unroll
            for (int j = 0; j < 8; ++j)
                xbf[base + j] = ftrunc_bf(((const float*)xsrc)[base + j]);
        } else {
            *(u16x8*)&xbf[base] = *(const u16x8*)&xsrc[base];
        }
    } else {
        const int bid = blockIdx.y * 32 + blockIdx.x;
        if (bid >= 28) return;
        const int e = bid * 256 + tid;
        int id, i;
        if (e < 3072)      { id = e >> 9;               i = e & 511;          }
        else if (e < 4096) { id = 6;                    i = e - 3072;         }
        else               { id = 7 + ((e - 4096) >> 9); i = (e - 4096) & 511; }
        const void* src;
        switch (id) {
            case 0: src = p0; break;  case 1: src = p1; break;
            case 2: src = p2; break;  case 3: src = p3; break;
            case 4: src = p4; break;  case 5: src = p5; break;
            case 6: src = p6; break;  case 7: src = p7; break;
            case 8: src = p8; break;  case 9: src = p9; break;
            case 10: src = p10; break; default: src = p11; break;
        }
        small[e] = isf ? ((const float*)src)[i] : bf2f(((const u16*)src)[i]);
    }
}

// ---------------------------------------------------------------------------
// MFMA GEMM (best-measured R6 config): out[N,M] = act(A@Wt^T + bias).
// TRxTC tile, BK=64, single-buffer staging, XOR-swizzled LDS, w=16 async.
// VOUT: for which==2, write transposed [B][H][HD][S] via LDS.
// ---------------------------------------------------------------------------
template <int TR, int TC, bool RELU, bool AWHICH, bool VOUT>
__global__ __launch_bounds__(256) void gemm_bt(
    const u16* __restrict__ Aall, const u16* __restrict__ Wtall,
    const float* __restrict__ ball, u16* __restrict__ out,
    u16* __restrict__ vtb, int N, int K, int M)
{
    constexpr int RT = TR / 32, CT = TC / 32;
    constexpr int AR = TR / 32, BR = TC / 32;
    constexpr int SSTAGE = (TR + TC) * 64;
    constexpr int SELEMS = VOUT ? (SSTAGE > TC * 136 ? SSTAGE : TC * 136) : SSTAGE;
    __shared__ __align__(16) u16 smem[SELEMS];
    u16* sA = smem;
    u16* sB = smem + TR * 64;

    const int mtiles = M / TC;
    const int which = blockIdx.x / mtiles;
    const int colb  = blockIdx.x % mtiles;
    const int row0 = blockIdx.y * TR, col0 = colb * TC;
    const u16* A  = Aall + (AWHICH ? (size_t)which * N * K : 0);
    const u16* Wt = Wtall + (size_t)which * M * K;
    const float* bias = ball + (size_t)which * M;

    const int tid = threadIdx.x;
    const int lane = tid & 63, w = tid >> 6;
    const int wrow = (w & 1) * (TR / 2), wcol = (w >> 1) * (TC / 2);
    const int c = lane & 15, quad = lane >> 4;

    const u16* ap[AR]; const u16* bp[BR];
    #pragma unroll
    for (int i = 0; i < AR; ++i) {
        const int raw = i * 256 + tid, r = raw >> 3, ch = (raw & 7) ^ (r & 7);
        ap[i] = A + (size_t)(row0 + r) * K + ch * 8;
    }
    #pragma unroll
    for (int i = 0; i < BR; ++i) {
        const int raw = i * 256 + tid, r = raw >> 3, ch = (raw & 7) ^ (r & 7);
        bp[i] = Wt + (size_t)(col0 + r) * K + ch * 8;
    }

    f32x4 acc[RT][CT] = {};

    for (int k0 = 0; k0 < K; k0 += 64) {
        __syncthreads();
        #pragma unroll
        for (int i = 0; i < AR; ++i) {
            async16(ap[i], (char*)sA + (i * 256 + tid) * 16);
            ap[i] += 64;
        }
        #pragma unroll
        for (int i = 0; i < BR; ++i) {
            async16(bp[i], (char*)sB + (i * 256 + tid) * 16);
            bp[i] += 64;
        }
        __syncthreads();

        #pragma unroll
        for (int kt = 0; kt < 2; ++kt) {
            bf16x8 af[RT], bfr[CT];
            #pragma unroll
            for (int rt = 0; rt < RT; ++rt) {
                const int r = wrow + rt * 16 + c;
                af[rt] = *(const bf16x8*)&sA[(r * 8 + ((kt * 4 + quad) ^ (r & 7))) * 8];
            }
            #pragma unroll
            for (int ct = 0; ct < CT; ++ct) {
                const int r = wcol + ct * 16 + c;
                bfr[ct] = *(const bf16x8*)&sB[(r * 8 + ((kt * 4 + quad) ^ (r & 7))) * 8];
            }
            #pragma unroll
            for (int rt = 0; rt < RT; ++rt)
                #pragma unroll
                for (int ct = 0; ct < CT; ++ct)
                    acc[rt][ct] = mfma16(af[rt], bfr[ct], acc[rt][ct]);
        }
    }

    if (VOUT && which == 2) {
        // transpose through LDS: smem[col][row], stride 136 (16B-aligned rows)
        __syncthreads();
        #pragma unroll
        for (int rt = 0; rt < RT; ++rt) {
            const int rowb = wrow + rt * 16 + quad * 4;
            #pragma unroll
            for (int ct = 0; ct < CT; ++ct) {
                const int col = wcol + ct * 16 + c;
                const float bb = bias[col0 + col];
                ushort4 pk;
                pk.x = ftrunc_bf(acc[rt][ct][0] + bb);
                pk.y = ftrunc_bf(acc[rt][ct][1] + bb);
                pk.z = ftrunc_bf(acc[rt][ct][2] + bb);
                pk.w = ftrunc_bf(acc[rt][ct][3] + bb);
                *(ushort4*)&smem[col * 136 + rowb] = pk;
            }
        }
        __syncthreads();
        const int dl = tid >> 1, half = tid & 1;         // TC=128 cols, 2x64 rows
        const int hg = (col0 + dl) >> 6, dd = (col0 + dl) & 63;
        const int bb = row0 >> 11, s0 = row0 & 2047;
        u16* dst = vtb + ((size_t)(bb * NH + hg) * HD + dd) * SS + s0 + half * 64;
        #pragma unroll
        for (int j = 0; j < 8; ++j)
            *(u16x8*)&dst[j * 8] = *(const u16x8*)&smem[dl * 136 + half * 64 + j * 8];
        return;
    }

    const size_t outW = (size_t)which * N * M;
    #pragma unroll
    for (int rt = 0; rt < RT; ++rt) {
        #pragma unroll
        for (int i = 0; i < 4; ++i) {
            const int row = row0 + wrow + rt * 16 + quad * 4 + i;
            #pragma unroll
            for (int ct = 0; ct < CT; ++ct) {
                const int col = col0 + wcol + ct * 16 + c;
                float v = acc[rt][ct][i] + bias[col];
                if (RELU) v = fmaxf(v, 0.0f);
                out[outW + (size_t)row * M + col] = ftrunc_bf(v);
            }
        }
    }
}

// ---------------------------------------------------------------------------
// MFMA flash attention. Q-tile 64 (grid 1024 = 4 blocks/CU), double-buffered
// K/V (40KB LDS -> 4 blocks/CU), XCD-pinned (b,h), no-max log2 softmax,
// per-wave sP round-trip; PV as O[d][q] = mfma(A=V^T, B=P^T) so the epilogue
// is coalesced and needs no l-broadcast.
// ---------------------------------------------------------------------------
__global__ __launch_bounds__(256) void attn_mfma(
    const u16* __restrict__ q, const u16* __restrict__ k,
    const u16* __restrict__ vt, u16* __restrict__ ctx)
{
    __shared__ __align__(16) u16 sK[2][64 * 64];
    __shared__ __align__(16) u16 sV[2][64 * 64];
    __shared__ __align__(16) u16 sP[4][16 * 64];

    const int tid = threadIdx.x;
    const int w = tid >> 6, lane = tid & 63;
    const int c = lane & 15, quad = lane >> 4;
    // XCD swizzle: id&7 = xcd; 128 slots/XCD = 4 bh x 32 q-tiles
    const int id = blockIdx.x;
    const int slot = id >> 3;
    const int bh = ((id & 7) << 2) | (slot >> 5);
    const int qt = slot & 31;
    const int b = bh >> 3, h = bh & 7;
    const int q0 = qt * 64;
    const size_t tokbase = (size_t)b * SS;
    const int hoff = h * HD;

    const int myq = q0 + w * 16 + c;
    bf16x8 qf[2];
    #pragma unroll
    for (int kt = 0; kt < 2; ++kt)
        qf[kt] = *(const bf16x8*)&q[(tokbase + myq) * EMB + hoff + kt * 32 + quad * 8];

    const u16* kp[2]; const u16* vp[2];
    #pragma unroll
    for (int i = 0; i < 2; ++i) {
        const int raw = i * 256 + tid, rr = raw >> 3, ch = (raw & 7) ^ (rr & 7);
        kp[i] = k + (tokbase + rr) * EMB + hoff + ch * 8;
        vp[i] = vt + ((size_t)(b * NH + h) * HD + rr) * SS + ch * 8;
    }
    auto stage = [&](int buf) {
        #pragma unroll
        for (int i = 0; i < 2; ++i) {
            async16(kp[i], (char*)&sK[buf][0] + (i * 256 + tid) * 16);
            kp[i] += 64 * EMB;
        }
        #pragma unroll
        for (int i = 0; i < 2; ++i) {
            async16(vp[i], (char*)&sV[buf][0] + (i * 256 + tid) * 16);
            vp[i] += 64;
        }
    };
    stage(0);

    float l_lane = 0.0f;
    f32x4 accO[4] = {};

    for (int t = 0; t < SS / 64; ++t) {
        __syncthreads();                 // drains stage(t), issued 1 iter ago
        const int buf = t & 1;
        if (t + 1 < SS / 64) stage(buf ^ 1);

        // S^T[key][q]: A = K-tile, B = Q^T. Lane (c,quad): q=c, keys mt*16+quad*4+i
        f32x4 accS[4] = {};
        #pragma unroll
        for (int mt = 0; mt < 4; ++mt) {
            const int key = mt * 16 + c;
            #pragma unroll
            for (int kt = 0; kt < 2; ++kt) {
                bf16x8 kf = *(const bf16x8*)&sK[buf][(key * 8 + ((kt * 4 + quad) ^ (key & 7))) * 8];
                accS[mt] = mfma16(kf, qf[kt], accS[mt]);
            }
        }

        // p = exp2(s*C2 + RB), pack bf16 pairs via v_perm
        u32 pw[8];
        float ls = 0.0f;
        #pragma unroll
        for (int mt = 0; mt < 4; ++mt) {
            const float e0 = __builtin_amdgcn_exp2f(fmaf(accS[mt][0], C2, RB));
            const float e1 = __builtin_amdgcn_exp2f(fmaf(accS[mt][1], C2, RB));
            const float e2 = __builtin_amdgcn_exp2f(fmaf(accS[mt][2], C2, RB));
            const float e3 = __builtin_amdgcn_exp2f(fmaf(accS[mt][3], C2, RB));
            ls += (e0 + e1) + (e2 + e3);
            pw[2 * mt]     = __builtin_amdgcn_perm(__float_as_uint(e1), __float_as_uint(e0), 0x07060302u);
            pw[2 * mt + 1] = __builtin_amdgcn_perm(__float_as_uint(e3), __float_as_uint(e2), 0x07060302u);
        }
        l_lane += ls;

        // write P^T -> sP[w][q=c][key], swizzled 16B blocks of 8 keys
        #pragma unroll
        for (int mt = 0; mt < 4; ++mt) {
            const int chunkW = 2 * mt + (quad >> 1);
            const int blk = c * 8 + (chunkW ^ (c & 7));
            uint2 u; u.x = pw[2 * mt]; u.y = pw[2 * mt + 1];
            *(uint2*)((char*)&sP[w][0] + blk * 16 + 8 * (quad & 1)) = u;
        }

        // PV: O[d][q] = mfma(A=V^T-frag, B=P^T-frag); pf doubles as B operand
        bf16x8 pf[2];
        #pragma unroll
        for (int kt = 0; kt < 2; ++kt)
            pf[kt] = *(const bf16x8*)&sP[w][(c * 8 + ((kt * 4 + quad) ^ (c & 7))) * 8];
        #pragma unroll
        for (int nt = 0; nt < 4; ++nt) {
            const int d = nt * 16 + c;
            #pragma unroll
            for (int kt = 0; kt < 2; ++kt) {
                bf16x8 vf = *(const bf16x8*)&sV[buf][(d * 8 + ((kt * 4 + quad) ^ (d & 7))) * 8];
                accO[nt] = mfma16(vf, pf[kt], accO[nt]);
            }
        }
    }

    // l for q=c: sum over quads
    float l = l_lane;
    l += __shfl_xor(l, 16);
    l += __shfl_xor(l, 32);
    const float li = (l > 0.0f) ? (1.0f / l) : 0.0f;

    // accO[nt] C-layout: col=c=q, row=quad*4+i = d-within-tile
    const int tok = q0 + w * 16 + c;
    u16* dst = ctx + (tokbase + tok) * EMB + hoff + quad * 4;
    #pragma unroll
    for (int nt = 0; nt < 4; ++nt) {
        ushort4 pk;
        pk.x = ftrunc_bf(accO[nt][0] * li);
        pk.y = ftrunc_bf(accO[nt][1] * li);
        pk.z = ftrunc_bf(accO[nt][2] * li);
        pk.w = ftrunc_bf(accO[nt][3] * li);
        *(ushort4*)&dst[nt * 16] = pk;
    }
}

// ---------------------------------------------------------------------------
// Residual + LayerNorm over EMB=512, bf16 in, one wave per row.
// ---------------------------------------------------------------------------
__global__ __launch_bounds__(256) void ln_mid(
    const u16* __restrict__ a, const u16* __restrict__ b2,
    const float* __restrict__ g, const float* __restrict__ be,
    u16* __restrict__ outb)
{
    const int wave = threadIdx.x >> 6, lane = threadIdx.x & 63;
    const size_t row = (size_t)blockIdx.x * 4 + wave;
    const u16x8 av = *(const u16x8*)&a[row * EMB + lane * 8];
    const u16x8 bv = *(const u16x8*)&b2[row * EMB + lane * 8];
    float vals[8], sum = 0.0f;
    #pragma unroll
    for (int i = 0; i < 8; ++i) { vals[i] = bf2f(av[i]) + bf2f(bv[i]); sum += vals[i]; }
    #pragma unroll
    for (int o = 1; o < 64; o <<= 1) sum += __shfl_xor(sum, o);
    const float mu = sum * (1.0f / 512.0f);
    float vs = 0.0f;
    #pragma unroll
    for (int i = 0; i < 8; ++i) { const float d = vals[i] - mu; vs += d * d; }
    #pragma unroll
    for (int o = 1; o < 64; o <<= 1) vs += __shfl_xor(vs, o);
    const float rstd = rsqrtf(vs * (1.0f / 512.0f) + EPS);
    u16x8 ov;
    #pragma unroll
    for (int i = 0; i < 8; ++i) {
        const int col = lane * 8 + i;
        ov[i] = f2bf((vals[i] - mu) * rstd * g[col] + be[col]);
    }
    *(u16x8*)&outb[row * EMB + lane * 8] = ov;
}

__global__ __launch_bounds__(256) void ln_final(
    const u16* __restrict__ a, const u16* __restrict__ b2,
    const float* __restrict__ g, const float* __restrict__ be,
    void* __restrict__ dout, const u16* __restrict__ xsrc)
{
    const int isf = derive_flag(xsrc);
    const int wave = threadIdx.x >> 6, lane = threadIdx.x & 63;
    const size_t row = (size_t)blockIdx.x * 4 + wave;
    const u16x8 av = *(const u16x8*)&a[row * EMB + lane * 8];
    const u16x8 bv = *(const u16x8*)&b2[row * EMB + lane * 8];
    float vals[8], sum = 0.0f;
    #pragma unroll
    for (int i = 0; i < 8; ++i) { vals[i] = bf2f(av[i]) + bf2f(bv[i]); sum += vals[i]; }
    #pragma unroll
    for (int o = 1; o < 64; o <<= 1) sum += __shfl_xor(sum, o);
    const float mu = sum * (1.0f / 512.0f);
    float vs = 0.0f;
    #pragma unroll
    for (int i = 0; i < 8; ++i) { const float d = vals[i] - mu; vs += d * d; }
    #pragma unroll
    for (int o = 1; o < 64; o <<= 1) vs += __shfl_xor(vs, o);
    const float rstd = rsqrtf(vs * (1.0f / 512.0f) + EPS);
    if (isf) {
        #pragma unroll
        for (int i = 0; i < 8; ++i) {
            const int col = lane * 8 + i;
            ((float*)dout)[row * EMB + col] = (vals[i] - mu) * rstd * g[col] + be[col];
        }
    } else {
        u16x8 ov;
        #pragma unroll
        for (int i = 0; i < 8; ++i) {
            const int col = lane * 8 + i;
            ov[i] = f2bf((vals[i] - mu) * rstd * g[col] + be[col]);
        }
        *(u16x8*)&((u16*)dout)[row * EMB + lane * 8] = ov;
    }
}

// ---------------------------------------------------------------------------
extern "C" void kernel_launch(void* const* d_in, const int* in_sizes, int n_in,
                              void* d_out, int out_size, void* d_ws, size_t ws_size,
                              hipStream_t stream)
{
    char* ws = (char*)d_ws;
    float* small = (float*)(ws + 0);        // 7168 f32
    u16*   wt1   = (u16*)(ws + 32768);
    u16*   wt2   = (u16*)(ws + 819200);
    u16*   f1t   = (u16*)(ws + 2392064);
    u16*   f2t   = (u16*)(ws + 3440640);
    u16*   xbf   = (u16*)(ws + 4489216);
    u16*   h3    = (u16*)(ws + 8683520);    // [3][NT][512]; reused as h2 [NT][1024]
    u16*   qkv   = (u16*)(ws + 33849344);   // [3][NT][512] (v slot unused)
    u16*   vtb   = (u16*)(ws + 59015168);   // [B][H][64][S]
    u16*   ctxb  = (u16*)(ws + 67403776);
    u16*   x1b   = (u16*)(ws + 75792384);
    u16*   ffb   = (u16*)(ws + 84180992);

    const dim3 blk(256);
    const u16* xsrc = (const u16*)d_in[0];

    prep<<<dim3(32, 32, 10), blk, 0, stream>>>(
        xsrc,
        d_in[1], d_in[5], d_in[9], d_in[3], d_in[7], d_in[11], d_in[13], d_in[15],
        d_in[2], d_in[6], d_in[10], d_in[4], d_in[8], d_in[12],
        d_in[14], d_in[16], d_in[17], d_in[18], d_in[19], d_in[20],
        xbf, wt1, wt2, f1t, f2t, small);

    // qkv layer 1: h3[which] = relu(x @ W1 + b1)
    gemm_bt<128, 128, true, false, false><<<dim3(12, 64), blk, 0, stream>>>(
        xbf, wt1, small + 0, h3, nullptr, NT, INF_, EMB);
    // qkv layer 2: q,k -> qkv; v -> vtb (transposed epilogue)
    gemm_bt<128, 128, false, true, true><<<dim3(12, 64), blk, 0, stream>>>(
        h3, wt2, small + 1536, qkv, vtb, NT, EMB, EMB);

    attn_mfma<<<dim3(1024), blk, 0, stream>>>(
        qkv, qkv + (size_t)NT * EMB, vtb, ctxb);

    // x1 = LN(ctx + q)
    ln_mid<<<NT / 4, blk, 0, stream>>>(ctxb, qkv, small + 4608, small + 5120, x1b);

    // FFN
    u16* h2 = h3;
    gemm_bt<128, 128, true, false, false><<<dim3(8, 64), blk, 0, stream>>>(
        x1b, f1t, small + 3072, h2, nullptr, NT, EMB, 1024);
    gemm_bt<128, 64, false, false, false><<<dim3(8, 64), blk, 0, stream>>>(
        h2, f2t, small + 4096, ffb, nullptr, NT, 1024, EMB);

    // out = LN(x1 + ff)
    ln_final<<<NT / 4, blk, 0, stream>>>(x1b, ffb, small + 5632, small + 6144, d_out, xsrc);
}

// Round 9
// 241.525 us; speedup vs baseline: 1.1324x; 1.0736x over previous
//
#include <hip/hip_runtime.h>
#include <hip/hip_bf16.h>
#include <math.h>

#define BB   4
#define SS   2048
#define INF_ 256
#define EMB  512
#define NH   8
#define HD   64
#define NT   8192

typedef unsigned short u16;
typedef unsigned int   u32;
typedef __attribute__((ext_vector_type(8))) short bf16x8;   // 8 bf16 = 4 VGPRs
typedef __attribute__((ext_vector_type(8))) unsigned short u16x8;
typedef __attribute__((ext_vector_type(4))) float f32x4;

constexpr float C2  = 0.06375871607f;    // (1/sqrt(512)) * log2(e)
constexpr float TB  = 1.00390625f;       // 1 + 2^-8
constexpr float EPS = 1e-5f;

__device__ __forceinline__ u16 f2bf(float v) {
    __hip_bfloat16 h = __float2bfloat16(v);
    return *(u16*)&h;
}
__device__ __forceinline__ float bf2f(u16 u) {
    __hip_bfloat16 h = *(__hip_bfloat16*)&u;
    return __bfloat162float(h);
}
__device__ __forceinline__ u16 ftrunc_bf(float v) {     // trunc + half-ulp bias
    return (u16)(__float_as_uint(v * TB) >> 16);
}
__device__ __forceinline__ f32x4 mfma16(bf16x8 a, bf16x8 b, f32x4 c) {
    return __builtin_amdgcn_mfma_f32_16x16x32_bf16(a, b, c, 0, 0, 0);
}
__device__ __forceinline__ void async16(const void* g, void* l) {
    __builtin_amdgcn_global_load_lds(
        (const __attribute__((address_space(1))) void*)g,
        (__attribute__((address_space(3))) void*)l, 16, 0, 0);
}
__device__ __forceinline__ int derive_flag(const u16* x) {
    const int lane = threadIdx.x & 63;
    const unsigned e = (x[lane * 2] >> 7) & 0xFF;
    float pl = (e == 0 || (e >= 110 && e <= 140)) ? 1.0f : 0.0f;
    #pragma unroll
    for (int o = 1; o < 64; o <<= 1) pl += __shfl_xor(pl, o);
    return pl < 32.0f;
}

// ---------------------------------------------------------------------------
// Fused prep: z 0..7 weight transpose W[K][M]->Wt[M][K] bf16; z=8 x->bf16;
// z=9 biases/ln params -> packed f32.
// ---------------------------------------------------------------------------
__global__ __launch_bounds__(256) void prep(
    const u16* __restrict__ xsrc,
    const void* w0, const void* w1, const void* w2, const void* w3,
    const void* w4, const void* w5, const void* w6, const void* w7,
    const void* p0, const void* p1, const void* p2, const void* p3,
    const void* p4, const void* p5, const void* p6, const void* p7,
    const void* p8, const void* p9, const void* p10, const void* p11,
    u16* __restrict__ xbf, u16* __restrict__ wt1, u16* __restrict__ wt2,
    u16* __restrict__ f1t, u16* __restrict__ f2t, float* __restrict__ small)
{
    const int isf = derive_flag(xsrc);
    const int z = blockIdx.z;
    const int tid = threadIdx.x;

    if (z < 8) {
        int K, M; const void* src; u16* dst;
        switch (z) {
            case 0: K=256;  M=512;  src=w0; dst=wt1;             break;
            case 1: K=256;  M=512;  src=w1; dst=wt1+512*256;     break;
            case 2: K=256;  M=512;  src=w2; dst=wt1+2*512*256;   break;
            case 3: K=512;  M=512;  src=w3; dst=wt2;             break;
            case 4: K=512;  M=512;  src=w4; dst=wt2+512*512;     break;
            case 5: K=512;  M=512;  src=w5; dst=wt2+2*512*512;   break;
            case 6: K=512;  M=1024; src=w6; dst=f1t;             break;
            default:K=1024; M=512;  src=w7; dst=f2t;             break;
        }
        const int m0 = blockIdx.x * 32, k0 = blockIdx.y * 32;
        if (m0 >= M || k0 >= K) return;
        __shared__ u16 t[32][33];
        const int tx = tid & 31, ty = tid >> 5;
        #pragma unroll
        for (int i = 0; i < 4; ++i) {
            const int kk = k0 + ty + i * 8;
            t[ty + i * 8][tx] = isf ? ftrunc_bf(((const float*)src)[(size_t)kk * M + m0 + tx])
                                    : ((const u16*)src)[(size_t)kk * M + m0 + tx];
        }
        __syncthreads();
        #pragma unroll
        for (int i = 0; i < 4; ++i) {
            const int mm = m0 + ty + i * 8;
            dst[(size_t)mm * K + k0 + tx] = t[tx][ty + i * 8];
        }
    } else if (z == 8) {
        const int bid = blockIdx.y * 32 + blockIdx.x;    // 0..1023
        const int base = bid * 2048 + tid * 8;
        if (isf) {
            #pragma unroll
            for (int j = 0; j < 8; ++j)
                xbf[base + j] = ftrunc_bf(((const float*)xsrc)[base + j]);
        } else {
            *(u16x8*)&xbf[base] = *(const u16x8*)&xsrc[base];
        }
    } else {
        const int bid = blockIdx.y * 32 + blockIdx.x;
        if (bid >= 28) return;
        const int e = bid * 256 + tid;
        int id, i;
        if (e < 3072)      { id = e >> 9;               i = e & 511;          }
        else if (e < 4096) { id = 6;                    i = e - 3072;         }
        else               { id = 7 + ((e - 4096) >> 9); i = (e - 4096) & 511; }
        const void* src;
        switch (id) {
            case 0: src = p0; break;  case 1: src = p1; break;
            case 2: src = p2; break;  case 3: src = p3; break;
            case 4: src = p4; break;  case 5: src = p5; break;
            case 6: src = p6; break;  case 7: src = p7; break;
            case 8: src = p8; break;  case 9: src = p9; break;
            case 10: src = p10; break; default: src = p11; break;
        }
        small[e] = isf ? ((const float*)src)[i] : bf2f(((const u16*)src)[i]);
    }
}

// ---------------------------------------------------------------------------
// MFMA GEMM, 64x64 tile (8 blocks/CU for latency hiding on short-K loops).
// Grid: x = row-tile (XCD-aligned A reuse), y = which*(M/64) + col-tile.
// 4 waves, each 32x32 (2x2 fragments). BK=64, XOR-swizzled LDS, w=16 async.
// SCALEK: which==1 output scaled by C2 (k only feeds attention).
// VOUT: which==2 written transposed to [B][H][HD][S] via LDS.
// ---------------------------------------------------------------------------
template <bool RELU, bool AWHICH, bool VOUT, bool SCALEK>
__global__ __launch_bounds__(256) void gemm64(
    const u16* __restrict__ Aall, const u16* __restrict__ Wtall,
    const float* __restrict__ ball, u16* __restrict__ out,
    u16* __restrict__ vtb, int N, int K, int M)
{
    __shared__ __align__(16) u16 sA[64 * 64];   // 8 KB
    __shared__ __align__(16) u16 sB[64 * 64];   // 8 KB

    const int mtiles = M >> 6;
    const int which = blockIdx.y / mtiles;
    const int colb  = blockIdx.y % mtiles;
    const int row0 = blockIdx.x << 6, col0 = colb << 6;
    const u16* A  = Aall + (AWHICH ? (size_t)which * N * K : 0);
    const u16* Wt = Wtall + (size_t)which * M * K;
    const float* bias = ball + (size_t)which * M;

    const int tid = threadIdx.x;
    const int lane = tid & 63, w = tid >> 6;
    const int wrow = (w & 1) << 5, wcol = (w >> 1) << 5;
    const int c = lane & 15, quad = lane >> 4;

    const u16* ap[2]; const u16* bp[2];
    #pragma unroll
    for (int i = 0; i < 2; ++i) {
        const int raw = i * 256 + tid, r = raw >> 3, ch = (raw & 7) ^ (r & 7);
        ap[i] = A + (size_t)(row0 + r) * K + ch * 8;
        bp[i] = Wt + (size_t)(col0 + r) * K + ch * 8;
    }

    f32x4 acc[2][2] = {};

    for (int k0 = 0; k0 < K; k0 += 64) {
        __syncthreads();
        #pragma unroll
        for (int i = 0; i < 2; ++i) {
            async16(ap[i], (char*)sA + (i * 256 + tid) * 16);
            ap[i] += 64;
            async16(bp[i], (char*)sB + (i * 256 + tid) * 16);
            bp[i] += 64;
        }
        __syncthreads();

        #pragma unroll
        for (int kt = 0; kt < 2; ++kt) {
            bf16x8 af[2], bfr[2];
            #pragma unroll
            for (int rt = 0; rt < 2; ++rt) {
                const int r = wrow + rt * 16 + c;
                af[rt] = *(const bf16x8*)&sA[(r * 8 + ((kt * 4 + quad) ^ (r & 7))) * 8];
            }
            #pragma unroll
            for (int ct = 0; ct < 2; ++ct) {
                const int r = wcol + ct * 16 + c;
                bfr[ct] = *(const bf16x8*)&sB[(r * 8 + ((kt * 4 + quad) ^ (r & 7))) * 8];
            }
            #pragma unroll
            for (int rt = 0; rt < 2; ++rt)
                #pragma unroll
                for (int ct = 0; ct < 2; ++ct)
                    acc[rt][ct] = mfma16(af[rt], bfr[ct], acc[rt][ct]);
        }
    }

    if (VOUT && which == 2) {
        // transpose through LDS: sA[col][row], stride 72 (144B rows, 16B-aligned)
        __syncthreads();
        #pragma unroll
        for (int rt = 0; rt < 2; ++rt) {
            const int rowb = wrow + rt * 16 + quad * 4;
            #pragma unroll
            for (int ct = 0; ct < 2; ++ct) {
                const int col = wcol + ct * 16 + c;
                const float bb = bias[col0 + col];
                ushort4 pk;
                pk.x = ftrunc_bf(acc[rt][ct][0] + bb);
                pk.y = ftrunc_bf(acc[rt][ct][1] + bb);
                pk.z = ftrunc_bf(acc[rt][ct][2] + bb);
                pk.w = ftrunc_bf(acc[rt][ct][3] + bb);
                *(ushort4*)&sA[col * 72 + rowb] = pk;
            }
        }
        __syncthreads();
        const int dl = tid >> 2, part = tid & 3;         // 64 cols x 4 row-parts
        const int hg = (col0 + dl) >> 6, dd = (col0 + dl) & 63;
        const int bb = row0 >> 11, s0 = row0 & 2047;
        u16* dst = vtb + ((size_t)(bb * NH + hg) * HD + dd) * SS + s0 + part * 16;
        #pragma unroll
        for (int j = 0; j < 2; ++j)
            *(u16x8*)&dst[j * 8] = *(const u16x8*)&sA[dl * 72 + part * 16 + j * 8];
        return;
    }

    const float sc = (SCALEK && which == 1) ? C2 : 1.0f;
    const size_t outW = (size_t)which * N * M;
    #pragma unroll
    for (int rt = 0; rt < 2; ++rt) {
        #pragma unroll
        for (int i = 0; i < 4; ++i) {
            const int row = row0 + wrow + rt * 16 + quad * 4 + i;
            #pragma unroll
            for (int ct = 0; ct < 2; ++ct) {
                const int col = col0 + wcol + ct * 16 + c;
                float v = (acc[rt][ct][i] + bias[col]) * sc;
                if (RELU) v = fmaxf(v, 0.0f);
                out[outW + (size_t)row * M + col] = ftrunc_bf(v);
            }
        }
    }
}

// ---------------------------------------------------------------------------
// MFMA flash attention. Q-tile 64, double-buffered K/V, XCD-pinned (b,h).
// K pre-scaled by C2 => p = exp2(accS) directly (no fma, no clamp).
// l via ones-MFMA on the truncated P fragments (exactly consistent with PV),
// so no per-iter adds and no cross-lane reductions at all.
// ---------------------------------------------------------------------------
__global__ __launch_bounds__(256) void attn_mfma(
    const u16* __restrict__ q, const u16* __restrict__ k,
    const u16* __restrict__ vt, u16* __restrict__ ctx)
{
    __shared__ __align__(16) u16 sK[2][64 * 64];
    __shared__ __align__(16) u16 sV[2][64 * 64];
    __shared__ __align__(16) u16 sP[4][16 * 64];

    const int tid = threadIdx.x;
    const int w = tid >> 6, lane = tid & 63;
    const int c = lane & 15, quad = lane >> 4;
    // XCD swizzle: id&7 = xcd; 128 slots/XCD = 4 bh x 32 q-tiles
    const int id = blockIdx.x;
    const int slot = id >> 3;
    const int bh = ((id & 7) << 2) | (slot >> 5);
    const int qt = slot & 31;
    const int b = bh >> 3, h = bh & 7;
    const int q0 = qt * 64;
    const size_t tokbase = (size_t)b * SS;
    const int hoff = h * HD;

    const int myq = q0 + w * 16 + c;
    bf16x8 qf[2];
    #pragma unroll
    for (int kt = 0; kt < 2; ++kt)
        qf[kt] = *(const bf16x8*)&q[(tokbase + myq) * EMB + hoff + kt * 32 + quad * 8];

    union { u32 u[4]; bf16x8 v; } ones;
    #pragma unroll
    for (int i = 0; i < 4; ++i) ones.u[i] = 0x3F803F80u;   // bf16 1.0 pairs

    const u16* kp[2]; const u16* vp[2];
    #pragma unroll
    for (int i = 0; i < 2; ++i) {
        const int raw = i * 256 + tid, rr = raw >> 3, ch = (raw & 7) ^ (rr & 7);
        kp[i] = k + (tokbase + rr) * EMB + hoff + ch * 8;
        vp[i] = vt + ((size_t)(b * NH + h) * HD + rr) * SS + ch * 8;
    }
    auto stage = [&](int buf) {
        #pragma unroll
        for (int i = 0; i < 2; ++i) {
            async16(kp[i], (char*)&sK[buf][0] + (i * 256 + tid) * 16);
            kp[i] += 64 * EMB;
        }
        #pragma unroll
        for (int i = 0; i < 2; ++i) {
            async16(vp[i], (char*)&sV[buf][0] + (i * 256 + tid) * 16);
            vp[i] += 64;
        }
    };
    stage(0);

    f32x4 accO[4] = {};
    f32x4 accL = {};

    for (int t = 0; t < SS / 64; ++t) {
        __syncthreads();                 // drains stage(t), issued 1 iter ago
        const int buf = t & 1;
        if (t + 1 < SS / 64) stage(buf ^ 1);

        // S^T[key][q]: A = K-tile (pre-scaled by C2), B = Q^T
        f32x4 accS[4] = {};
        #pragma unroll
        for (int mt = 0; mt < 4; ++mt) {
            const int key = mt * 16 + c;
            #pragma unroll
            for (int kt = 0; kt < 2; ++kt) {
                bf16x8 kf = *(const bf16x8*)&sK[buf][(key * 8 + ((kt * 4 + quad) ^ (key & 7))) * 8];
                accS[mt] = mfma16(kf, qf[kt], accS[mt]);
            }
        }

        // p = exp2(s'), pack bf16 pairs via v_perm (truncation)
        u32 pw[8];
        #pragma unroll
        for (int mt = 0; mt < 4; ++mt) {
            const float e0 = __builtin_amdgcn_exp2f(accS[mt][0]);
            const float e1 = __builtin_amdgcn_exp2f(accS[mt][1]);
            const float e2 = __builtin_amdgcn_exp2f(accS[mt][2]);
            const float e3 = __builtin_amdgcn_exp2f(accS[mt][3]);
            pw[2 * mt]     = __builtin_amdgcn_perm(__float_as_uint(e1), __float_as_uint(e0), 0x07060302u);
            pw[2 * mt + 1] = __builtin_amdgcn_perm(__float_as_uint(e3), __float_as_uint(e2), 0x07060302u);
        }

        // write P^T -> sP[w][q=c][key], swizzled 16B blocks of 8 keys
        #pragma unroll
        for (int mt = 0; mt < 4; ++mt) {
            const int chunkW = 2 * mt + (quad >> 1);
            const int blk = c * 8 + (chunkW ^ (c & 7));
            uint2 u; u.x = pw[2 * mt]; u.y = pw[2 * mt + 1];
            *(uint2*)((char*)&sP[w][0] + blk * 16 + 8 * (quad & 1)) = u;
        }

        // PV: O[d][q] = mfma(A=V^T-frag, B=P^T-frag); l[q] = mfma(A=ones, B=P)
        bf16x8 pf[2];
        #pragma unroll
        for (int kt = 0; kt < 2; ++kt)
            pf[kt] = *(const bf16x8*)&sP[w][(c * 8 + ((kt * 4 + quad) ^ (c & 7))) * 8];
        accL = mfma16(ones.v, pf[0], accL);
        accL = mfma16(ones.v, pf[1], accL);
        #pragma unroll
        for (int nt = 0; nt < 4; ++nt) {
            const int d = nt * 16 + c;
            #pragma unroll
            for (int kt = 0; kt < 2; ++kt) {
                bf16x8 vf = *(const bf16x8*)&sV[buf][(d * 8 + ((kt * 4 + quad) ^ (d & 7))) * 8];
                accO[nt] = mfma16(vf, pf[kt], accO[nt]);
            }
        }
    }

    // accL rows are identical; accL[0] = full l for q=c (no reduction needed)
    const float l = accL[0];
    const float li = (l > 0.0f) ? (1.0f / l) : 0.0f;

    // accO[nt] C-layout: col=c=q, row=quad*4+i = d-within-tile
    const int tok = q0 + w * 16 + c;
    u16* dst = ctx + (tokbase + tok) * EMB + hoff + quad * 4;
    #pragma unroll
    for (int nt = 0; nt < 4; ++nt) {
        ushort4 pk;
        pk.x = ftrunc_bf(accO[nt][0] * li);
        pk.y = ftrunc_bf(accO[nt][1] * li);
        pk.z = ftrunc_bf(accO[nt][2] * li);
        pk.w = ftrunc_bf(accO[nt][3] * li);
        *(ushort4*)&dst[nt * 16] = pk;
    }
}

// ---------------------------------------------------------------------------
// Residual + LayerNorm over EMB=512, bf16 in, one wave per row.
// ---------------------------------------------------------------------------
__global__ __launch_bounds__(256) void ln_mid(
    const u16* __restrict__ a, const u16* __restrict__ b2,
    const float* __restrict__ g, const float* __restrict__ be,
    u16* __restrict__ outb)
{
    const int wave = threadIdx.x >> 6, lane = threadIdx.x & 63;
    const size_t row = (size_t)blockIdx.x * 4 + wave;
    const u16x8 av = *(const u16x8*)&a[row * EMB + lane * 8];
    const u16x8 bv = *(const u16x8*)&b2[row * EMB + lane * 8];
    float vals[8], sum = 0.0f;
    #pragma unroll
    for (int i = 0; i < 8; ++i) { vals[i] = bf2f(av[i]) + bf2f(bv[i]); sum += vals[i]; }
    #pragma unroll
    for (int o = 1; o < 64; o <<= 1) sum += __shfl_xor(sum, o);
    const float mu = sum * (1.0f / 512.0f);
    float vs = 0.0f;
    #pragma unroll
    for (int i = 0; i < 8; ++i) { const float d = vals[i] - mu; vs += d * d; }
    #pragma unroll
    for (int o = 1; o < 64; o <<= 1) vs += __shfl_xor(vs, o);
    const float rstd = rsqrtf(vs * (1.0f / 512.0f) + EPS);
    u16x8 ov;
    #pragma unroll
    for (int i = 0; i < 8; ++i) {
        const int col = lane * 8 + i;
        ov[i] = f2bf((vals[i] - mu) * rstd * g[col] + be[col]);
    }
    *(u16x8*)&outb[row * EMB + lane * 8] = ov;
}

__global__ __launch_bounds__(256) void ln_final(
    const u16* __restrict__ a, const u16* __restrict__ b2,
    const float* __restrict__ g, const float* __restrict__ be,
    void* __restrict__ dout, const u16* __restrict__ xsrc)
{
    const int isf = derive_flag(xsrc);
    const int wave = threadIdx.x >> 6, lane = threadIdx.x & 63;
    const size_t row = (size_t)blockIdx.x * 4 + wave;
    const u16x8 av = *(const u16x8*)&a[row * EMB + lane * 8];
    const u16x8 bv = *(const u16x8*)&b2[row * EMB + lane * 8];
    float vals[8], sum = 0.0f;
    #pragma unroll
    for (int i = 0; i < 8; ++i) { vals[i] = bf2f(av[i]) + bf2f(bv[i]); sum += vals[i]; }
    #pragma unroll
    for (int o = 1; o < 64; o <<= 1) sum += __shfl_xor(sum, o);
    const float mu = sum * (1.0f / 512.0f);
    float vs = 0.0f;
    #pragma unroll
    for (int i = 0; i < 8; ++i) { const float d = vals[i] - mu; vs += d * d; }
    #pragma unroll
    for (int o = 1; o < 64; o <<= 1) vs += __shfl_xor(vs, o);
    const float rstd = rsqrtf(vs * (1.0f / 512.0f) + EPS);
    if (isf) {
        #pragma unroll
        for (int i = 0; i < 8; ++i) {
            const int col = lane * 8 + i;
            ((float*)dout)[row * EMB + col] = (vals[i] - mu) * rstd * g[col] + be[col];
        }
    } else {
        u16x8 ov;
        #pragma unroll
        for (int i = 0; i < 8; ++i) {
            const int col = lane * 8 + i;
            ov[i] = f2bf((vals[i] - mu) * rstd * g[col] + be[col]);
        }
        *(u16x8*)&((u16*)dout)[row * EMB + lane * 8] = ov;
    }
}

// ---------------------------------------------------------------------------
extern "C" void kernel_launch(void* const* d_in, const int* in_sizes, int n_in,
                              void* d_out, int out_size, void* d_ws, size_t ws_size,
                              hipStream_t stream)
{
    char* ws = (char*)d_ws;
    float* small = (float*)(ws + 0);        // 7168 f32
    u16*   wt1   = (u16*)(ws + 32768);
    u16*   wt2   = (u16*)(ws + 819200);
    u16*   f1t   = (u16*)(ws + 2392064);
    u16*   f2t   = (u16*)(ws + 3440640);
    u16*   xbf   = (u16*)(ws + 4489216);
    u16*   h3    = (u16*)(ws + 8683520);    // [3][NT][512]; reused as h2 [NT][1024]
    u16*   qkv   = (u16*)(ws + 33849344);   // [3][NT][512] (v slot unused)
    u16*   vtb   = (u16*)(ws + 59015168);   // [B][H][64][S]
    u16*   ctxb  = (u16*)(ws + 67403776);
    u16*   x1b   = (u16*)(ws + 75792384);
    u16*   ffb   = (u16*)(ws + 84180992);

    const dim3 blk(256);
    const u16* xsrc = (const u16*)d_in[0];

    prep<<<dim3(32, 32, 10), blk, 0, stream>>>(
        xsrc,
        d_in[1], d_in[5], d_in[9], d_in[3], d_in[7], d_in[11], d_in[13], d_in[15],
        d_in[2], d_in[6], d_in[10], d_in[4], d_in[8], d_in[12],
        d_in[14], d_in[16], d_in[17], d_in[18], d_in[19], d_in[20],
        xbf, wt1, wt2, f1t, f2t, small);

    // qkv layer 1: h3[which] = relu(x @ W1 + b1)   grid (rowtiles, which*ctiles)
    gemm64<true, false, false, false><<<dim3(128, 24), blk, 0, stream>>>(
        xbf, wt1, small + 0, h3, nullptr, NT, INF_, EMB);
    // qkv layer 2: q -> qkv[0]; k*C2 -> qkv[1]; v -> vtb (transposed)
    gemm64<false, true, true, true><<<dim3(128, 24), blk, 0, stream>>>(
        h3, wt2, small + 1536, qkv, vtb, NT, EMB, EMB);

    attn_mfma<<<dim3(1024), blk, 0, stream>>>(
        qkv, qkv + (size_t)NT * EMB, vtb, ctxb);

    // x1 = LN(ctx + q)
    ln_mid<<<NT / 4, blk, 0, stream>>>(ctxb, qkv, small + 4608, small + 5120, x1b);

    // FFN
    u16* h2 = h3;
    gemm64<true, false, false, false><<<dim3(128, 16), blk, 0, stream>>>(
        x1b, f1t, small + 3072, h2, nullptr, NT, EMB, 1024);
    gemm64<false, false, false, false><<<dim3(128, 8), blk, 0, stream>>>(
        h2, f2t, small + 4096, ffb, nullptr, NT, 1024, EMB);

    // out = LN(x1 + ff)
    ln_final<<<NT / 4, blk, 0, stream>>>(x1b, ffb, small + 5632, small + 6144, d_out, xsrc);
}